// Round 1
// baseline (5024.327 us; speedup 1.0000x reference)
//
#include <hip/hip_runtime.h>

#define HW 128
#define HW2 (128 * 128)
#define NEG 0.2f

__device__ __forceinline__ float lrelu(float v) { return v >= 0.f ? v : NEG * v; }

// ---------------------------------------------------------------------------
// Plain 3x3 conv, SAME padding, optional LeakyReLU.
// Block: 256 threads = 8x32 output tile. blockIdx.y picks CO output channels.
// Input patch staged in LDS; weights read with wave-uniform indices (s_load).
// ---------------------------------------------------------------------------
template <int CO>
__global__ __launch_bounds__(256) void conv3x3_kernel(
    const float* __restrict__ in, const float* __restrict__ w,
    const float* __restrict__ bias, float* __restrict__ out,
    int Cin, int Cout, int do_leaky)
{
    __shared__ float sp[10][34];

    const int t = threadIdx.x;
    const int b = blockIdx.z;
    const int tile = blockIdx.x;          // 0..63 -> 4 x-tiles, 16 y-tiles
    const int tx0 = (tile & 3) * 32;
    const int ty0 = (tile >> 2) * 8;
    const int lx = t & 31, ly = t >> 5;
    const int y = ty0 + ly, x = tx0 + lx;
    const int co0 = blockIdx.y * CO;

    float acc[CO];
#pragma unroll
    for (int j = 0; j < CO; ++j) acc[j] = 0.f;

    const float* inb = in + (size_t)b * Cin * HW2;

    for (int c = 0; c < Cin; ++c) {
        const float* plane = inb + (size_t)c * HW2;
        // stage 10x34 patch (zero-padded)
        for (int i = t; i < 340; i += 256) {
            int r = i / 34, cc = i - r * 34;
            int gy = ty0 + r - 1, gx = tx0 + cc - 1;
            float v = 0.f;
            if (gy >= 0 && gy < HW && gx >= 0 && gx < HW) v = plane[gy * HW + gx];
            sp[r][cc] = v;
        }
        __syncthreads();

        float pv[9];
#pragma unroll
        for (int i = 0; i < 3; ++i)
#pragma unroll
            for (int j = 0; j < 3; ++j) pv[i * 3 + j] = sp[ly + i][lx + j];

        const float* wc = w + ((size_t)co0 * Cin + c) * 9;
#pragma unroll
        for (int j = 0; j < CO; ++j) {
            const float* wj = wc + (size_t)j * Cin * 9;
#pragma unroll
            for (int k = 0; k < 9; ++k) acc[j] = fmaf(pv[k], wj[k], acc[j]);
        }
        __syncthreads();
    }

#pragma unroll
    for (int j = 0; j < CO; ++j) {
        float v = acc[j] + bias[co0 + j];
        if (do_leaky) v = lrelu(v);
        out[(((size_t)b * Cout + co0 + j) * HW + y) * HW + x] = v;
    }
}

// ---------------------------------------------------------------------------
// Deformable 3x3 conv (torchvision semantics), bias + LeakyReLU.
// Block: 256 threads = 64 pixels (8x8 tile) x 4 co-sets (each COT channels).
// Phase 0: per-tap bilinear corner indices + validity-masked weights -> LDS.
// Per input channel: phase A gathers/interpolates val[64][9] once into LDS
// (no duplication across output channels), phase B does the co-dot with
// wave-uniform weight reads.
// ---------------------------------------------------------------------------
template <int COT>
__global__ __launch_bounds__(256) void deform_kernel(
    const float* __restrict__ in, const float* __restrict__ off,
    const float* __restrict__ w, const float* __restrict__ bias,
    float* __restrict__ out, int Cin, int Cout)
{
    __shared__ float s_wt[64][9][4];
    __shared__ int s_idx[64][9][4];
    __shared__ float s_val[64][9];

    const int t = threadIdx.x;
    const int b = blockIdx.z;
    const int tile = blockIdx.x;          // 0..255 -> 16x16 grid of 8x8 tiles
    const int tx0 = (tile & 15) * 8;
    const int ty0 = (tile >> 4) * 8;
    const int px = t & 63;
    const int set = t >> 6;               // wave-uniform
    const int y = ty0 + (px >> 3);
    const int x = tx0 + (px & 7);

    // Phase 0: tap parameters (64 px * 9 taps = 576 tasks)
    const float* offb = off + (size_t)b * 18 * HW2;
    for (int task = t; task < 576; task += 256) {
        int p = task / 9, k = task - p * 9;
        int yy = ty0 + (p >> 3), xx = tx0 + (p & 7);
        float dy = offb[(2 * k) * HW2 + yy * HW + xx];
        float dx = offb[(2 * k + 1) * HW2 + yy * HW + xx];
        float py = (float)(yy + k / 3 - 1) + dy;
        float pxx = (float)(xx + k % 3 - 1) + dx;
        float fy = floorf(py), fx = floorf(pxx);
        float wy = py - fy, wx = pxx - fx;
        int iy = (int)fy, ix = (int)fx;
        int iy1 = iy + 1, ix1 = ix + 1;
        float vy0 = (iy >= 0 && iy < HW) ? 1.f : 0.f;
        float vy1 = (iy1 >= 0 && iy1 < HW) ? 1.f : 0.f;
        float vx0 = (ix >= 0 && ix < HW) ? 1.f : 0.f;
        float vx1 = (ix1 >= 0 && ix1 < HW) ? 1.f : 0.f;
        int cy0 = min(max(iy, 0), HW - 1), cy1 = min(max(iy1, 0), HW - 1);
        int cx0 = min(max(ix, 0), HW - 1), cx1 = min(max(ix1, 0), HW - 1);
        s_wt[p][k][0] = (1.f - wy) * (1.f - wx) * vy0 * vx0;
        s_wt[p][k][1] = (1.f - wy) * wx * vy0 * vx1;
        s_wt[p][k][2] = wy * (1.f - wx) * vy1 * vx0;
        s_wt[p][k][3] = wy * wx * vy1 * vx1;
        s_idx[p][k][0] = cy0 * HW + cx0;
        s_idx[p][k][1] = cy0 * HW + cx1;
        s_idx[p][k][2] = cy1 * HW + cx0;
        s_idx[p][k][3] = cy1 * HW + cx1;
    }
    __syncthreads();

    float acc[COT];
#pragma unroll
    for (int j = 0; j < COT; ++j) acc[j] = 0.f;

    const float* inb = in + (size_t)b * Cin * HW2;

    for (int c = 0; c < Cin; ++c) {
        const float* plane = inb + (size_t)c * HW2;
        // Phase A: bilinear gather -> s_val
        for (int task = t; task < 576; task += 256) {
            int p = task / 9, k = task - p * 9;
            int4 id = *(const int4*)&s_idx[p][k][0];
            float4 wt = *(const float4*)&s_wt[p][k][0];
            float v = wt.x * plane[id.x] + wt.y * plane[id.y] +
                      wt.z * plane[id.z] + wt.w * plane[id.w];
            s_val[p][k] = v;
        }
        __syncthreads();

        // Phase B: accumulate COT output channels for this pixel
        float v[9];
#pragma unroll
        for (int k = 0; k < 9; ++k) v[k] = s_val[px][k];
        const float* wc = w + ((size_t)(set * COT) * Cin + c) * 9;
#pragma unroll
        for (int j = 0; j < COT; ++j) {
            const float* wj = wc + (size_t)j * Cin * 9;
#pragma unroll
            for (int k = 0; k < 9; ++k) acc[j] = fmaf(v[k], wj[k], acc[j]);
        }
        __syncthreads();
    }

#pragma unroll
    for (int j = 0; j < COT; ++j) {
        int co = set * COT + j;
        float v2 = lrelu(acc[j] + bias[co]);
        out[(((size_t)b * Cout + co) * HW + y) * HW + x] = v2;
    }
}

// ---------------------------------------------------------------------------
static void conv_launch(const float* in, const float* w, const float* b,
                        float* out, int Cin, int Cout, int leaky,
                        hipStream_t s)
{
    if (Cout % 32 == 0) {
        dim3 g(64, Cout / 32, 4);
        conv3x3_kernel<32><<<g, 256, 0, s>>>(in, w, b, out, Cin, Cout, leaky);
    } else {  // offset conv, Cout = 18
        dim3 g(64, 1, 4);
        conv3x3_kernel<18><<<g, 256, 0, s>>>(in, w, b, out, Cin, Cout, leaky);
    }
}

static void deform_launch(const float* in, const float* off, const float* w,
                          const float* b, float* out, int Cin, int Cout,
                          hipStream_t s)
{
    dim3 g(256, 1, 4);
    if (Cout == 128)
        deform_kernel<32><<<g, 256, 0, s>>>(in, off, w, b, out, Cin, Cout);
    else  // Cout == 64
        deform_kernel<16><<<g, 256, 0, s>>>(in, off, w, b, out, Cin, Cout);
}

extern "C" void kernel_launch(void* const* d_in, const int* in_sizes, int n_in,
                              void* d_out, int out_size, void* d_ws,
                              size_t ws_size, hipStream_t stream)
{
    const float* x = (const float*)d_in[0];
    const float* p[18];
    for (int i = 0; i < 18; ++i) p[i] = (const float*)d_in[1 + i];

    float* A = (float*)d_ws;                       // up to (4,128,128,128)
    float* Bf = A + (size_t)4 * 128 * HW2;         // up to (4,128,128,128)
    float* OFF = Bf + (size_t)4 * 128 * HW2;       // (4,18,128,128)
    float* OUT = (float*)d_out;

    // Stage 1: 64 -> 128
    conv_launch(x, p[0], p[1], A, 64, 128, 1, stream);
    conv_launch(A, p[2], p[3], OFF, 128, 18, 0, stream);
    deform_launch(A, OFF, p[4], p[5], Bf, 128, 128, stream);

    // Stage 2: 128 -> 128
    conv_launch(Bf, p[6], p[7], A, 128, 128, 1, stream);
    conv_launch(A, p[8], p[9], OFF, 128, 18, 0, stream);
    deform_launch(A, OFF, p[10], p[11], Bf, 128, 128, stream);

    // Stage 3: 128 -> 64
    conv_launch(Bf, p[12], p[13], A, 128, 64, 1, stream);
    conv_launch(A, p[14], p[15], OFF, 64, 18, 0, stream);
    deform_launch(A, OFF, p[16], p[17], OUT, 64, 64, stream);
}